// Round 1
// baseline (428.347 us; speedup 1.0000x reference)
//
#include <hip/hip_runtime.h>

// IntraSentenceAttention: out[b,i,:] = sum_j e_ij * x[b,j,:] / (sum_j e_ij + EPS)
//   e_ij = exp(dot(x_i,x_j) + min(i-j,10)) * m_i * m_j
// B=32, T=1024, D=128, fp32. No online rescale needed (scores <= ~12.3).

constexpr int Tn = 1024;
constexpr int Dn = 128;
constexpr int BM = 64;     // query rows per block
constexpr int BN = 64;     // key rows per tile
constexpr int KS = 128;    // LDS float-stride for Q/K tiles (XOR-swizzled)
constexpr float EPSF = 1e-7f;

// swizzle: float4-chunk c4 of row r stored at c4 ^ ((r>>2)&7)
__device__ __forceinline__ int swz(int row, int c4) {
    return (c4 ^ ((row >> 2) & 7));
}

__global__ __launch_bounds__(256, 2)
void attn_fused(const float* __restrict__ x, const int* __restrict__ mask,
                float* __restrict__ out) {
    __shared__ float Qs[BM * KS];      // 32 KB
    __shared__ float Ks[BN * KS];      // 32 KB
    __shared__ float Pt[BN * BM];      // 16 KB, transposed: Pt[j][i]
    __shared__ float mks[BN];

    const int t  = threadIdx.x;        // 0..255
    const int b  = blockIdx.y;
    const int i0 = blockIdx.x * BM;

    const float* xb = x + (size_t)b * Tn * Dn;

    // ---- load Q tile (64x128 floats = 2048 float4s, 8 per thread) ----
    #pragma unroll
    for (int k = 0; k < 8; ++k) {
        int idx = t + k * 256;
        int r = idx >> 5, c4 = idx & 31;
        float4 v = *(const float4*)(xb + (size_t)(i0 + r) * Dn + c4 * 4);
        *(float4*)(&Qs[r * KS + swz(r, c4) * 4]) = v;
    }

    // S-stage coords: 16x16 threads, each computes 4x4 scores
    const int sx = t & 15, sy = t >> 4;
    // PV-stage coords: 16 d-groups (8 floats) x 16 row-groups (4 rows)
    const int pc = t & 15, pr = t >> 4;

    float acc[4][8];
    float den[4] = {0.f, 0.f, 0.f, 0.f};
    #pragma unroll
    for (int r = 0; r < 4; ++r)
        #pragma unroll
        for (int c = 0; c < 8; ++c) acc[r][c] = 0.f;

    for (int jt = 0; jt < Tn / BN; ++jt) {
        const int j0 = jt * BN;
        __syncthreads();   // previous PV done reading Ks/Pt

        // ---- load K tile + mask tile ----
        #pragma unroll
        for (int k = 0; k < 8; ++k) {
            int idx = t + k * 256;
            int r = idx >> 5, c4 = idx & 31;
            float4 v = *(const float4*)(xb + (size_t)(j0 + r) * Dn + c4 * 4);
            *(float4*)(&Ks[r * KS + swz(r, c4) * 4]) = v;
        }
        if (t < BN) mks[t] = (mask[b * Tn + j0 + t] != 0) ? 1.0f : 0.0f;
        __syncthreads();

        // ---- S = Q * K^T, 4x4 fragment per thread ----
        float s[4][4];
        #pragma unroll
        for (int r = 0; r < 4; ++r)
            #pragma unroll
            for (int c = 0; c < 4; ++c) s[r][c] = 0.f;

        #pragma unroll 4
        for (int d4 = 0; d4 < Dn / 4; ++d4) {
            float4 q[4], kk[4];
            #pragma unroll
            for (int r = 0; r < 4; ++r)
                q[r] = *(const float4*)(&Qs[(4 * sy + r) * KS + (d4 ^ (sy & 7)) * 4]);
            #pragma unroll
            for (int c = 0; c < 4; ++c)
                kk[c] = *(const float4*)(&Ks[(4 * sx + c) * KS + (d4 ^ (sx & 7)) * 4]);
            #pragma unroll
            for (int r = 0; r < 4; ++r)
                #pragma unroll
                for (int c = 0; c < 4; ++c) {
                    s[r][c] += q[r].x * kk[c].x + q[r].y * kk[c].y
                             + q[r].z * kk[c].z + q[r].w * kk[c].w;
                }
        }

        // ---- exp(S + dist) * m_j -> Pt (transposed) ----
        #pragma unroll
        for (int r = 0; r < 4; ++r) {
            int i = i0 + 4 * sy + r;
            #pragma unroll
            for (int c = 0; c < 4; ++c) {
                int j = j0 + 4 * sx + c;
                int di = i - j;
                float dist = (float)(di < 10 ? di : 10);
                float e = __expf(s[r][c] + dist) * mks[4 * sx + c];
                Pt[(4 * sx + c) * BM + (4 * sy + r)] = e;
            }
        }
        __syncthreads();

        // ---- PV: acc[r][d] += P[row][j] * K[j][d]; den[r] += P[row][j] ----
        #pragma unroll 4
        for (int j = 0; j < BN; ++j) {
            float4 p4 = *(const float4*)(&Pt[j * BM + 4 * pr]);
            int sw = (j >> 2) & 7;
            float4 k0 = *(const float4*)(&Ks[j * KS + ((2 * pc)     ^ sw) * 4]);
            float4 k1 = *(const float4*)(&Ks[j * KS + ((2 * pc + 1) ^ sw) * 4]);
            float pv[4] = {p4.x, p4.y, p4.z, p4.w};
            #pragma unroll
            for (int r = 0; r < 4; ++r) {
                den[r] += pv[r];
                acc[r][0] += pv[r] * k0.x;
                acc[r][1] += pv[r] * k0.y;
                acc[r][2] += pv[r] * k0.z;
                acc[r][3] += pv[r] * k0.w;
                acc[r][4] += pv[r] * k1.x;
                acc[r][5] += pv[r] * k1.y;
                acc[r][6] += pv[r] * k1.z;
                acc[r][7] += pv[r] * k1.w;
            }
        }
    }

    // ---- epilogue: out = m_i * num / (den + EPS) ----
    const int* mrow = mask + (size_t)b * Tn + i0;
    float* ob = out + ((size_t)b * Tn + i0) * Dn;
    #pragma unroll
    for (int r = 0; r < 4; ++r) {
        int row = 4 * pr + r;
        float mi = (mrow[row] != 0) ? 1.0f : 0.0f;
        float inv = mi / (den[r] + EPSF);
        float4 o0, o1;
        o0.x = acc[r][0] * inv; o0.y = acc[r][1] * inv;
        o0.z = acc[r][2] * inv; o0.w = acc[r][3] * inv;
        o1.x = acc[r][4] * inv; o1.y = acc[r][5] * inv;
        o1.z = acc[r][6] * inv; o1.w = acc[r][7] * inv;
        *(float4*)(&ob[(size_t)row * Dn + 8 * pc    ]) = o0;
        *(float4*)(&ob[(size_t)row * Dn + 8 * pc + 4]) = o1;
    }
}

extern "C" void kernel_launch(void* const* d_in, const int* in_sizes, int n_in,
                              void* d_out, int out_size, void* d_ws, size_t ws_size,
                              hipStream_t stream) {
    const float* x    = (const float*)d_in[0];
    const int*   mask = (const int*)d_in[1];
    float*       out  = (float*)d_out;
    const int B = in_sizes[1] / Tn;   // 32
    dim3 grid(Tn / BM, B);
    attn_fused<<<grid, 256, 0, stream>>>(x, mask, out);
}

// Round 2
// 114.372 us; speedup vs baseline: 3.7452x; 3.7452x over previous
//
#include <hip/hip_runtime.h>

// IntraSentenceAttention, MFMA bf16 version.
// out[b,i,:] = m_i * sum_j e_ij x[b,j,:] / (sum_j e_ij + EPS)
//   e_ij = exp(dot(x_i,x_j) + min(i-j,10)) * m_j
// B=32, T=1024, D=128. Scores <= ~12.3 -> no online-softmax rescale needed.

typedef __bf16 bf16x8 __attribute__((ext_vector_type(8)));
typedef float  f32x4  __attribute__((ext_vector_type(4)));

constexpr int Tn = 1024;
constexpr int Dn = 128;
constexpr int BM = 64;
constexpr int BN = 64;
constexpr float EPSF = 1e-7f;

// ============================ pre-pass kernels ============================

// x fp32 [n] -> xb bf16 [n]
__global__ void cvt_bf16(const float* __restrict__ x, __bf16* __restrict__ xb, int n) {
    int i = (blockIdx.x * blockDim.x + threadIdx.x) * 8;
    if (i >= n) return;
    float4 a = *(const float4*)(x + i);
    float4 b = *(const float4*)(x + i + 4);
    bf16x8 v;
    v[0] = (__bf16)a.x; v[1] = (__bf16)a.y; v[2] = (__bf16)a.z; v[3] = (__bf16)a.w;
    v[4] = (__bf16)b.x; v[5] = (__bf16)b.y; v[6] = (__bf16)b.z; v[7] = (__bf16)b.w;
    *(bf16x8*)(xb + i) = v;
}

// x fp32 [b][t][d] -> xt bf16 [b][d][t]; 64(t) x 64(d) LDS tiles
__global__ void transpose_bf16(const float* __restrict__ x, __bf16* __restrict__ xt) {
    __shared__ float tile[64][65];
    const int b = blockIdx.z, t0 = blockIdx.x * 64, d0 = blockIdx.y * 64;
    const int t = threadIdx.x;
    #pragma unroll
    for (int k = 0; k < 4; ++k) {
        int cid = t + k * 256;
        int r = cid >> 4, c4 = cid & 15;           // row t0+r, float4-chunk of d
        float4 v = *(const float4*)(x + ((size_t)(b * Tn + t0 + r) * Dn) + d0 + c4 * 4);
        tile[r][c4 * 4 + 0] = v.x; tile[r][c4 * 4 + 1] = v.y;
        tile[r][c4 * 4 + 2] = v.z; tile[r][c4 * 4 + 3] = v.w;
    }
    __syncthreads();
    #pragma unroll
    for (int k = 0; k < 2; ++k) {
        int cid = t + k * 256;
        int dd = cid >> 3, t8 = cid & 7;           // out row d0+dd, t-chunk of 8
        bf16x8 v;
        #pragma unroll
        for (int j = 0; j < 8; ++j) v[j] = (__bf16)tile[t8 * 8 + j][dd];
        *(bf16x8*)(xt + ((size_t)(b * Dn + d0 + dd) * Tn) + t0 + t8 * 8) = v;
    }
}

// ============================ main MFMA kernel ============================
// LDS layouts (chunk = 16B = 8 bf16, XOR-swizzled to keep all patterns <=2-way):
//   Kb [j(64)][d(128)]  : chunk c of row r stored at c ^ (r & 15)   (16 chunks/row)
//   KTb[d(128)][j(64)]  : chunk c of row d stored at c ^ (d & 7)    (8 chunks/row)
//   Pb [i(64)][j(64)]   : chunk c of row i stored at c ^ (i & 7)

__global__ __launch_bounds__(256, 3)
void attn_mfma(const __bf16* __restrict__ Xb, const __bf16* __restrict__ XbT,
               const int* __restrict__ mask, float* __restrict__ out) {
    __shared__ __align__(16) __bf16 Kb[64 * 128];    // 16 KB
    __shared__ __align__(16) __bf16 KTb[128 * 64];   // 16 KB
    __shared__ __align__(16) __bf16 Pb[64 * 64];     // 8 KB
    __shared__ float mks[64];

    const int t = threadIdx.x, w = t >> 6, l = t & 63;
    const int b = blockIdx.y, i0 = blockIdx.x * BM;
    const int m = l & 15, quad = l >> 4;

    const __bf16* xb  = Xb  + (size_t)b * Tn * Dn;
    const __bf16* xtb = XbT + (size_t)b * Dn * Tn;

    // Q A-fragments for this wave's 16-row strip, held in registers all kernel.
    // A[mrow = lane&15][k = quad*8 + j], k-chunks kt*32 (m120-verified layout).
    bf16x8 aq[4];
    {
        const __bf16* qrow = xb + (size_t)(i0 + 16 * w + m) * Dn + quad * 8;
        #pragma unroll
        for (int kt = 0; kt < 4; ++kt) aq[kt] = *(const bf16x8*)(qrow + kt * 32);
    }

    f32x4 acc[8];
    #pragma unroll
    for (int n2 = 0; n2 < 8; ++n2) acc[n2] = (f32x4){0.f, 0.f, 0.f, 0.f};
    float dreg = 0.f;   // den for row (l&15) of this wave's strip

    for (int jt = 0; jt < Tn / BN; ++jt) {
        const int j0 = jt * BN;
        __syncthreads();

        // ---- stage K tile (row-major + transposed) ----
        #pragma unroll
        for (int kk = 0; kk < 4; ++kk) {
            int cid = t + kk * 256;
            int r = cid >> 4, c = cid & 15;
            bf16x8 v = *(const bf16x8*)(xb + (size_t)(j0 + r) * Dn + c * 8);
            *(bf16x8*)(Kb + r * 128 + (c ^ (r & 15)) * 8) = v;
        }
        #pragma unroll
        for (int kk = 0; kk < 4; ++kk) {
            int cid = t + kk * 256;
            int d = cid >> 3, c = cid & 7;
            bf16x8 v = *(const bf16x8*)(xtb + (size_t)d * Tn + j0 + c * 8);
            *(bf16x8*)(KTb + d * 64 + (c ^ (d & 7)) * 8) = v;
        }
        if (t < 64) mks[t] = (mask[b * Tn + j0 + t] != 0) ? 1.f : 0.f;
        __syncthreads();

        // ---- S = Q * K^T : wave strip 16 x 64, 4 n-tiles x 4 k-chunks ----
        f32x4 cs[4];
        #pragma unroll
        for (int nt = 0; nt < 4; ++nt) cs[nt] = (f32x4){0.f, 0.f, 0.f, 0.f};
        #pragma unroll
        for (int nt = 0; nt < 4; ++nt) {
            const int row = nt * 16 + m;   // K row (B-frag n = lane&15)
            #pragma unroll
            for (int kt = 0; kt < 4; ++kt) {
                bf16x8 bk = *(const bf16x8*)(Kb + row * 128 + ((kt * 4 + quad) ^ (row & 15)) * 8);
                cs[nt] = __builtin_amdgcn_mfma_f32_16x16x32_bf16(aq[kt], bk, cs[nt], 0, 0, 0);
            }
        }

        // ---- P = exp(S + dist) * m_j, write to Pb (C-layout -> LDS) ----
        // C/D: col = lane&15, row = quad*4 + reg  (m89-verified)
        #pragma unroll
        for (int nt = 0; nt < 4; ++nt) {
            const int j = j0 + nt * 16 + m;
            const float mj = mks[nt * 16 + m];
            const int pcol = nt * 16 + m;
            #pragma unroll
            for (int r = 0; r < 4; ++r) {
                const int i = i0 + 16 * w + quad * 4 + r;
                const int di = i - j;
                const float dist = (float)(di < 10 ? di : 10);
                const float e = __expf(cs[nt][r] + dist) * mj;
                const int prow = 16 * w + quad * 4 + r;
                Pb[prow * 64 + ((pcol >> 3) ^ (prow & 7)) * 8 + (pcol & 7)] = (__bf16)e;
            }
        }
        __syncthreads();

        // ---- PV: O += P * K ; A = Pb rows strip, B = KTb rows (= K columns) ----
        bf16x8 ap[2];
        #pragma unroll
        for (int k2 = 0; k2 < 2; ++k2) {
            const int prow = 16 * w + m;
            ap[k2] = *(const bf16x8*)(Pb + prow * 64 + ((k2 * 4 + quad) ^ (prow & 7)) * 8);
        }
        // den from the rounded P (self-consistent with PV)
        float dp = 0.f;
        #pragma unroll
        for (int k2 = 0; k2 < 2; ++k2)
            #pragma unroll
            for (int j = 0; j < 8; ++j) dp += (float)ap[k2][j];
        dp += __shfl_xor(dp, 16);
        dp += __shfl_xor(dp, 32);
        dreg += dp;

        #pragma unroll
        for (int n2 = 0; n2 < 8; ++n2) {
            const int drow = n2 * 16 + m;  // KTb row = global d (B-frag n = lane&15)
            #pragma unroll
            for (int k2 = 0; k2 < 2; ++k2) {
                bf16x8 bk = *(const bf16x8*)(KTb + drow * 64 + ((k2 * 4 + quad) ^ (drow & 7)) * 8);
                acc[n2] = __builtin_amdgcn_mfma_f32_16x16x32_bf16(ap[k2], bk, acc[n2], 0, 0, 0);
            }
        }
    }

    // ---- epilogue ----
    #pragma unroll
    for (int r = 0; r < 4; ++r) {
        const int i = i0 + 16 * w + quad * 4 + r;
        const float den = __shfl(dreg, quad * 4 + r, 64);
        const float mi = (mask[b * Tn + i] != 0) ? 1.f : 0.f;
        const float inv = mi / (den + EPSF);
        float* orow = out + (size_t)(b * Tn + i) * Dn;
        #pragma unroll
        for (int n2 = 0; n2 < 8; ++n2)
            orow[n2 * 16 + m] = acc[n2][r] * inv;
    }
}

// ===================== fallback fp32 kernel (round 1) =====================

constexpr int KS = 128;
__device__ __forceinline__ int swz(int row, int c4) { return (c4 ^ ((row >> 2) & 7)); }

__global__ __launch_bounds__(256, 2)
void attn_fused(const float* __restrict__ x, const int* __restrict__ mask,
                float* __restrict__ out) {
    __shared__ float Qs[BM * KS];
    __shared__ float Ks[BN * KS];
    __shared__ float Pt[BN * BM];
    __shared__ float mks[BN];

    const int t  = threadIdx.x;
    const int b  = blockIdx.y;
    const int i0 = blockIdx.x * BM;
    const float* xb = x + (size_t)b * Tn * Dn;

    #pragma unroll
    for (int k = 0; k < 8; ++k) {
        int idx = t + k * 256;
        int r = idx >> 5, c4 = idx & 31;
        float4 v = *(const float4*)(xb + (size_t)(i0 + r) * Dn + c4 * 4);
        *(float4*)(&Qs[r * KS + swz(r, c4) * 4]) = v;
    }
    const int sx = t & 15, sy = t >> 4;
    const int pc = t & 15, pr = t >> 4;
    float acc[4][8];
    float den[4] = {0.f, 0.f, 0.f, 0.f};
    #pragma unroll
    for (int r = 0; r < 4; ++r)
        #pragma unroll
        for (int c = 0; c < 8; ++c) acc[r][c] = 0.f;

    for (int jt = 0; jt < Tn / BN; ++jt) {
        const int j0 = jt * BN;
        __syncthreads();
        #pragma unroll
        for (int k = 0; k < 8; ++k) {
            int idx = t + k * 256;
            int r = idx >> 5, c4 = idx & 31;
            float4 v = *(const float4*)(xb + (size_t)(j0 + r) * Dn + c4 * 4);
            *(float4*)(&Ks[r * KS + swz(r, c4) * 4]) = v;
        }
        if (t < BN) mks[t] = (mask[b * Tn + j0 + t] != 0) ? 1.0f : 0.0f;
        __syncthreads();

        float s[4][4];
        #pragma unroll
        for (int r = 0; r < 4; ++r)
            #pragma unroll
            for (int c = 0; c < 4; ++c) s[r][c] = 0.f;
        #pragma unroll 4
        for (int d4 = 0; d4 < Dn / 4; ++d4) {
            float4 q[4], kk[4];
            #pragma unroll
            for (int r = 0; r < 4; ++r)
                q[r] = *(const float4*)(&Qs[(4 * sy + r) * KS + (d4 ^ (sy & 7)) * 4]);
            #pragma unroll
            for (int c = 0; c < 4; ++c)
                kk[c] = *(const float4*)(&Ks[(4 * sx + c) * KS + (d4 ^ (sx & 7)) * 4]);
            #pragma unroll
            for (int r = 0; r < 4; ++r)
                #pragma unroll
                for (int c = 0; c < 4; ++c)
                    s[r][c] += q[r].x * kk[c].x + q[r].y * kk[c].y
                             + q[r].z * kk[c].z + q[r].w * kk[c].w;
        }
        #pragma unroll
        for (int r = 0; r < 4; ++r) {
            int i = i0 + 4 * sy + r;
            #pragma unroll
            for (int c = 0; c < 4; ++c) {
                int j = j0 + 4 * sx + c;
                int di = i - j;
                float dist = (float)(di < 10 ? di : 10);
                float e = __expf(s[r][c] + dist) * mks[4 * sx + c];
                Pt[(4 * sx + c) * BM + (4 * sy + r)] = e;
            }
        }
        __syncthreads();
        #pragma unroll 4
        for (int j = 0; j < BN; ++j) {
            float4 p4 = *(const float4*)(&Pt[j * BM + 4 * pr]);
            int sw = (j >> 2) & 7;
            float4 k0 = *(const float4*)(&Ks[j * KS + ((2 * pc)     ^ sw) * 4]);
            float4 k1 = *(const float4*)(&Ks[j * KS + ((2 * pc + 1) ^ sw) * 4]);
            float pv[4] = {p4.x, p4.y, p4.z, p4.w};
            #pragma unroll
            for (int r = 0; r < 4; ++r) {
                den[r] += pv[r];
                acc[r][0] += pv[r] * k0.x; acc[r][1] += pv[r] * k0.y;
                acc[r][2] += pv[r] * k0.z; acc[r][3] += pv[r] * k0.w;
                acc[r][4] += pv[r] * k1.x; acc[r][5] += pv[r] * k1.y;
                acc[r][6] += pv[r] * k1.z; acc[r][7] += pv[r] * k1.w;
            }
        }
    }
    const int* mrow = mask + (size_t)b * Tn + i0;
    float* ob = out + ((size_t)b * Tn + i0) * Dn;
    #pragma unroll
    for (int r = 0; r < 4; ++r) {
        int row = 4 * pr + r;
        float mi = (mrow[row] != 0) ? 1.0f : 0.0f;
        float inv = mi / (den[r] + EPSF);
        float4 o0, o1;
        o0.x = acc[r][0] * inv; o0.y = acc[r][1] * inv;
        o0.z = acc[r][2] * inv; o0.w = acc[r][3] * inv;
        o1.x = acc[r][4] * inv; o1.y = acc[r][5] * inv;
        o1.z = acc[r][6] * inv; o1.w = acc[r][7] * inv;
        *(float4*)(&ob[(size_t)row * Dn + 8 * pc    ]) = o0;
        *(float4*)(&ob[(size_t)row * Dn + 8 * pc + 4]) = o1;
    }
}

// ================================ launch ================================

extern "C" void kernel_launch(void* const* d_in, const int* in_sizes, int n_in,
                              void* d_out, int out_size, void* d_ws, size_t ws_size,
                              hipStream_t stream) {
    const float* x    = (const float*)d_in[0];
    const int*   mask = (const int*)d_in[1];
    float*       out  = (float*)d_out;
    const int nx = in_sizes[0];          // B*T*D
    const int B  = in_sizes[1] / Tn;

    const size_t need = (size_t)nx * 2 * 2;   // Xb + XbT, bf16
    if (ws_size >= need) {
        __bf16* Xb  = (__bf16*)d_ws;
        __bf16* XbT = Xb + nx;
        cvt_bf16<<<nx / (8 * 256), 256, 0, stream>>>(x, Xb, nx);
        dim3 tg(Tn / 64, Dn / 64, B);
        transpose_bf16<<<tg, 256, 0, stream>>>(x, XbT);
        dim3 grid(Tn / BM, B);
        attn_mfma<<<grid, 256, 0, stream>>>(Xb, XbT, mask, out);
    } else {
        dim3 grid(Tn / BM, B);
        attn_fused<<<grid, 256, 0, stream>>>(x, mask, out);
    }
}

// Round 4
// 106.346 us; speedup vs baseline: 4.0278x; 1.0755x over previous
//
#include <hip/hip_runtime.h>

// IntraSentenceAttention, single-kernel MFMA bf16 (no workspace — the harness
// re-poisons d_ws (268 MB, ~46 us) inside the timed region when ws is used).
// out[b,i,:] = m_i * sum_j e_ij x[b,j,:] / (sum_j e_ij + EPS)
//   e_ij = exp(dot(x_i,x_j) + min(i-j,10)) * m_j
// B=32, T=1024, D=128. Scores <= ~12.3 -> no online-softmax rescale needed.
//
// Transposed compute: stage1 S^T = K * Q^T  (A=K rows, B=Q frags)
//                     stage2 O^T = K^T * P^T (A=KT rows, B=P rows)
// fp32 x is loaded directly, converted to bf16 while staging into LDS;
// the K^T tile is built by scalar transpose writes (swizzled, <=2-way).

typedef __bf16 bf16x8 __attribute__((ext_vector_type(8)));
typedef __bf16 bf16x4 __attribute__((ext_vector_type(4)));
typedef float  f32x4  __attribute__((ext_vector_type(4)));

constexpr int Tn = 1024;
constexpr int Dn = 128;
constexpr int BM = 64;
constexpr int BN = 64;
constexpr float EPSF = 1e-7f;

// KTb per-row chunk swizzle: must mix d>>3 so the scalar transpose writes
// (lanes vary d = c8*8+q, fixed q) spread across banks. <=3-bit result.
__device__ __forceinline__ int ktf(int d) { return ((d >> 3) ^ d) & 7; }

__global__ __launch_bounds__(256, 2)
void attn_mfma(const float* __restrict__ x, const int* __restrict__ mask,
               float* __restrict__ out) {
    __shared__ __align__(16) __bf16 Kb[64 * 128];    // 16 KB  [j][d], chunk c at c^(j&15)
    __shared__ __align__(16) __bf16 KTb[128 * 64];   // 16 KB  [d][j], chunk c at c^ktf(d)
    __shared__ __align__(16) __bf16 Pb[64 * 64];     // 8 KB   [i][j], chunk c at c^(i&7)
    __shared__ __align__(16) float mb[64];           // mask bias (0 / -1e5)

    const int t = threadIdx.x, w = t >> 6, l = t & 63;
    const int m = l & 15, quad = l >> 4;
    // XCD-affinity decode: bid%8 == b%8 -> all 16 i-tiles of a batch share an XCD.
    const int bid = blockIdx.x;
    const int b   = bid & 31;
    const int i0  = (bid >> 5) * BM;
    const float* xb = x + (size_t)b * Tn * Dn;

    // ---- Q fragments in registers all kernel: Q[i0+16w+m][kt*32+quad*8+j] ----
    bf16x8 aq[4];
    {
        const float* qrow = xb + (size_t)(i0 + 16 * w + m) * Dn + quad * 8;
        #pragma unroll
        for (int kt = 0; kt < 4; ++kt) {
            float4 a = *(const float4*)(qrow + kt * 32);
            float4 c = *(const float4*)(qrow + kt * 32 + 4);
            bf16x8 v;
            v[0] = (__bf16)a.x; v[1] = (__bf16)a.y; v[2] = (__bf16)a.z; v[3] = (__bf16)a.w;
            v[4] = (__bf16)c.x; v[5] = (__bf16)c.y; v[6] = (__bf16)c.z; v[7] = (__bf16)c.w;
            aq[kt] = v;
        }
    }

    // staging coords: thread covers rows sr+kk*16, 8-float chunk c8
    const int sr = t >> 4, c8 = t & 15;

    // ---- prefetch tile 0 (fp32, 8 floats per kk) ----
    float4 pfa[4], pfb[4];
    #pragma unroll
    for (int kk = 0; kk < 4; ++kk) {
        const float* p = xb + (size_t)(sr + kk * 16) * Dn + c8 * 8;
        pfa[kk] = *(const float4*)p;
        pfb[kk] = *(const float4*)(p + 4);
    }
    float mbreg = 0.f;
    if (t < 64) mbreg = (mask[b * Tn + t] != 0) ? 0.f : -1e5f;

    f32x4 acc[8];
    #pragma unroll
    for (int n2 = 0; n2 < 8; ++n2) acc[n2] = (f32x4){0.f, 0.f, 0.f, 0.f};
    float dsum = 0.f;                        // den partial for i = i0+16w+m
    const float fi = (float)(i0 + 16 * w + m);

    for (int jt = 0; jt < Tn / BN; ++jt) {
        const int j0 = jt * BN;
        __syncthreads();                     // prev tile's readers done

        // ---- commit staged registers to LDS (convert fp32->bf16 here) ----
        #pragma unroll
        for (int kk = 0; kk < 4; ++kk) {
            const int r = sr + kk * 16;
            bf16x8 v;
            v[0] = (__bf16)pfa[kk].x; v[1] = (__bf16)pfa[kk].y;
            v[2] = (__bf16)pfa[kk].z; v[3] = (__bf16)pfa[kk].w;
            v[4] = (__bf16)pfb[kk].x; v[5] = (__bf16)pfb[kk].y;
            v[6] = (__bf16)pfb[kk].z; v[7] = (__bf16)pfb[kk].w;
            *(bf16x8*)(Kb + r * 128 + ((c8 ^ (r & 15)) * 8)) = v;
            // transpose into KTb: element (d = c8*8+q, j-col = r)
            #pragma unroll
            for (int q = 0; q < 8; ++q) {
                const int d = c8 * 8 + q;
                KTb[d * 64 + (((r >> 3) ^ ktf(d)) * 8) + (r & 7)] = v[q];
            }
        }
        if (t < 64) mb[t] = mbreg;
        __syncthreads();

        // ---- prefetch next tile (in flight across the whole compute) ----
        const int jn = (jt + 1 < Tn / BN) ? (j0 + BN) : j0;
        #pragma unroll
        for (int kk = 0; kk < 4; ++kk) {
            const float* p = xb + (size_t)(jn + sr + kk * 16) * Dn + c8 * 8;
            pfa[kk] = *(const float4*)p;
            pfb[kk] = *(const float4*)(p + 4);
        }
        if (t < 64) mbreg = (mask[b * Tn + jn + t] != 0) ? 0.f : -1e5f;

        // ---- stage 1: S^T = K*Q^T (4 j-subtiles), exp -> Pb ----
        const float fdbase = fi - (float)(j0 + quad * 4);
        #pragma unroll
        for (int nt = 0; nt < 4; ++nt) {
            const int arow = nt * 16 + m;                 // K row (A-frag m)
            f32x4 cs = (f32x4){0.f, 0.f, 0.f, 0.f};
            #pragma unroll
            for (int kt = 0; kt < 4; ++kt) {
                bf16x8 av = *(const bf16x8*)(Kb + arow * 128 +
                               (((kt * 4 + quad) ^ (arow & 15)) * 8));
                cs = __builtin_amdgcn_mfma_f32_16x16x32_bf16(av, aq[kt], cs, 0, 0, 0);
            }
            // C layout: col = i-local = l&15 (fixed), row = j = nt*16+quad*4+r
            float4 m4 = *(const float4*)&mb[nt * 16 + quad * 4];
            const float base = fdbase - (float)(nt * 16);
            bf16x4 pv;
            #pragma unroll
            for (int r = 0; r < 4; ++r) {
                float di   = base - (float)r;             // i - j
                float dist = fminf(di, 10.f);
                float e = __expf(cs[r] + dist + ((const float*)&m4)[r]);
                dsum += e;
                pv[r] = (__bf16)e;
            }
            const int irow = 16 * w + m;
            const int jc = nt * 2 + (quad >> 1);          // 8-chunk index
            *(bf16x4*)(Pb + irow * 64 + ((jc ^ (m & 7)) * 8) + (quad & 1) * 4) = pv;
        }

        // ---- stage 2: O^T += K^T * P^T (Pb rows wave-private: no barrier) ----
        const int prow = 16 * w + m;
        bf16x8 ap[2];
        #pragma unroll
        for (int k2 = 0; k2 < 2; ++k2)
            ap[k2] = *(const bf16x8*)(Pb + prow * 64 +
                         (((k2 * 4 + quad) ^ (prow & 7)) * 8));
        #pragma unroll
        for (int n2 = 0; n2 < 8; ++n2) {
            const int drow = n2 * 16 + m;                 // KT row = global d
            #pragma unroll
            for (int k2 = 0; k2 < 2; ++k2) {
                bf16x8 av = *(const bf16x8*)(KTb + drow * 64 +
                               (((k2 * 4 + quad) ^ ktf(drow)) * 8));
                acc[n2] = __builtin_amdgcn_mfma_f32_16x16x32_bf16(av, ap[k2], acc[n2], 0, 0, 0);
            }
        }
    }

    // ---- epilogue: O^T C-layout col = i, rows d = n2*16 + quad*4 + r ----
    dsum += __shfl_xor(dsum, 16);
    dsum += __shfl_xor(dsum, 32);
    const int i = i0 + 16 * w + m;
    const float mi = (mask[b * Tn + i] != 0) ? 1.f : 0.f;
    const float inv = mi / (dsum + EPSF);
    float* orow = out + (size_t)(b * Tn + i) * Dn;
    #pragma unroll
    for (int n2 = 0; n2 < 8; ++n2) {
        float4 o;
        o.x = acc[n2][0] * inv; o.y = acc[n2][1] * inv;
        o.z = acc[n2][2] * inv; o.w = acc[n2][3] * inv;
        *(float4*)(orow + n2 * 16 + quad * 4) = o;
    }
}

// ============================ launch ============================
extern "C" void kernel_launch(void* const* d_in, const int* in_sizes, int n_in,
                              void* d_out, int out_size, void* d_ws, size_t ws_size,
                              hipStream_t stream) {
    const float* x    = (const float*)d_in[0];
    const int*   mask = (const int*)d_in[1];
    float*       out  = (float*)d_out;
    const int B = in_sizes[1] / Tn;          // 32
    const int nblocks = B * (Tn / BM);       // 512, bid%8 == batch%8
    attn_mfma<<<nblocks, 256, 0, stream>>>(x, mask, out);
}

// Round 5
// 103.426 us; speedup vs baseline: 4.1416x; 1.0282x over previous
//
#include <hip/hip_runtime.h>

// IntraSentenceAttention, single-kernel MFMA bf16, double-buffered staging.
// out[b,i,:] = m_i * sum_j e_ij x[b,j,:] / (sum_j e_ij + EPS)
//   e_ij = exp(dot(x_i,x_j) + min(i-j,10)) * m_j
// B=32, T=1024, D=128. Scores <= ~12.3 -> no online-softmax rescale needed.
//
// stage1 S^T = K * Q^T  (A=Kb rows, B=Q register frags)
// stage2 O^T = K^T * P^T (A=KTb rows, B=Pb rows)
// Double-buffered Kb/KTb: one barrier per tile; staging writes overlap compute.
// Staging: thread owns 2 rows x 4 d per unit -> Kb b64 writes (<=2-way),
// KTb transposed b32 row-pair writes (~4-way max, half the instructions).

typedef __bf16 bf16x8 __attribute__((ext_vector_type(8)));
typedef __bf16 bf16x4 __attribute__((ext_vector_type(4)));
typedef __bf16 bf16x2 __attribute__((ext_vector_type(2)));
typedef float  f32x4  __attribute__((ext_vector_type(4)));

constexpr int Tn = 1024;
constexpr int Dn = 128;
constexpr int BM = 64;
constexpr int BN = 64;
constexpr int NT = Tn / BN;      // 16 j-tiles
constexpr float EPSF = 1e-7f;

// KTb chunk swizzle: mixes d>>3 (3 bits) and d bit6 so transpose writes spread.
__device__ __forceinline__ int ktf3(int d) {
    return (((d >> 3) ^ d) & 7) ^ (((d >> 6) & 1) << 1);
}

__global__ __launch_bounds__(256, 2)
void attn_mfma(const float* __restrict__ x, const int* __restrict__ mask,
               float* __restrict__ out) {
    __shared__ __align__(16) __bf16 Kb[2][64 * 128];    // 2x16 KB [j][d], chunk c at c^(j&15)
    __shared__ __align__(16) __bf16 KTb[2][128 * 64];   // 2x16 KB [d][j], chunk c at c^ktf3(d)
    __shared__ __align__(16) __bf16 Pb[64 * 64];        // 8 KB    [i][j], chunk c at c^(i&7)
    __shared__ __align__(16) float mb[2][64];           // mask bias (0 / -1e5)

    const int t = threadIdx.x, w = t >> 6, l = t & 63;
    const int m = l & 15, quad = l >> 4;
    // bid%8 = batch%8 -> all 16 i-tile blocks of a batch share an XCD's L2.
    const int bid = blockIdx.x;
    const int b   = bid & 31;
    const int i0  = (bid >> 5) * BM;
    const float* xb = x + (size_t)b * Tn * Dn;

    // ---- Q fragments in registers all kernel: Q[i0+16w+m][kt*32+quad*8+j] ----
    bf16x8 aq[4];
    {
        const float* qrow = xb + (size_t)(i0 + 16 * w + m) * Dn + quad * 8;
        #pragma unroll
        for (int kt = 0; kt < 4; ++kt) {
            float4 a = *(const float4*)(qrow + kt * 32);
            float4 c = *(const float4*)(qrow + kt * 32 + 4);
            bf16x8 v;
            v[0] = (__bf16)a.x; v[1] = (__bf16)a.y; v[2] = (__bf16)a.z; v[3] = (__bf16)a.w;
            v[4] = (__bf16)c.x; v[5] = (__bf16)c.y; v[6] = (__bf16)c.z; v[7] = (__bf16)c.w;
            aq[kt] = v;
        }
    }

    // staging coords: thread owns rows r=2(pg+8kk), r+1 and d = 4*c4..4*c4+3
    const int c4 = t & 31, pg = t >> 5;

    float4 pf0[4], pf1[4];
    float  mreg = 0.f;

    auto load_tile = [&](int j0) {
        #pragma unroll
        for (int kk = 0; kk < 4; ++kk) {
            const int r = 2 * (pg + 8 * kk);
            const float* p = xb + (size_t)(j0 + r) * Dn + c4 * 4;
            pf0[kk] = *(const float4*)p;
            pf1[kk] = *(const float4*)(p + Dn);
        }
        if (t < 64) mreg = (mask[b * Tn + j0 + t] != 0) ? 0.f : -1e5f;
    };

    auto commit = [&](int bs) {
        #pragma unroll
        for (int kk = 0; kk < 4; ++kk) {
            const int r = 2 * (pg + 8 * kk);
            bf16x4 b0, b1;
            b0[0] = (__bf16)pf0[kk].x; b0[1] = (__bf16)pf0[kk].y;
            b0[2] = (__bf16)pf0[kk].z; b0[3] = (__bf16)pf0[kk].w;
            b1[0] = (__bf16)pf1[kk].x; b1[1] = (__bf16)pf1[kk].y;
            b1[2] = (__bf16)pf1[kk].z; b1[3] = (__bf16)pf1[kk].w;
            const int c8 = c4 >> 1, lo = (c4 & 1) * 4;
            *(bf16x4*)(&Kb[bs][r * 128       + ((c8 ^ (r & 15)) * 8)       + lo]) = b0;
            *(bf16x4*)(&Kb[bs][(r + 1) * 128 + ((c8 ^ ((r + 1) & 15)) * 8) + lo]) = b1;
            #pragma unroll
            for (int dd = 0; dd < 4; ++dd) {
                const int d = 4 * c4 + dd;
                bf16x2 pp; pp[0] = b0[dd]; pp[1] = b1[dd];
                *(bf16x2*)(&KTb[bs][d * 64 + (((r >> 3) ^ ktf3(d)) * 8) + (r & 7)]) = pp;
            }
        }
        if (t < 64) mb[bs][t] = mreg;
    };

    // pipeline prologue: tile0 -> buf0; tile1 -> regs
    load_tile(0);
    commit(0);
    load_tile(BN);

    f32x4 acc[8];
    #pragma unroll
    for (int n2 = 0; n2 < 8; ++n2) acc[n2] = (f32x4){0.f, 0.f, 0.f, 0.f};
    float dsum = 0.f;                       // den partial for i = i0+16w+m
    const float fi = (float)(i0 + 16 * w + m);

    for (int jt = 0; jt < NT; ++jt) {
        const int bs = jt & 1;
        const int j0 = jt * BN;
        __syncthreads();   // buf[bs] writes complete; buf[bs^1] readers done

        // commit tile jt+1 into the other buffer (writes overlap this tile's compute)
        commit(bs ^ 1);
        // prefetch tile jt+2
        const int jl = (jt + 2 < NT) ? (jt + 2) : (NT - 1);
        load_tile(jl * BN);

        // ---- stage 1: S^T = K*Q^T (4 j-subtiles), exp -> Pb ----
        const float fdbase = fi - (float)(j0 + quad * 4);
        #pragma unroll
        for (int nt = 0; nt < 4; ++nt) {
            const int arow = nt * 16 + m;                 // K row (A-frag m)
            f32x4 cs = (f32x4){0.f, 0.f, 0.f, 0.f};
            #pragma unroll
            for (int kt = 0; kt < 4; ++kt) {
                bf16x8 av = *(const bf16x8*)(&Kb[bs][arow * 128 +
                               (((kt * 4 + quad) ^ (arow & 15)) * 8)]);
                cs = __builtin_amdgcn_mfma_f32_16x16x32_bf16(av, aq[kt], cs, 0, 0, 0);
            }
            // C layout: col = i-local = l&15 (fixed), row = j = nt*16+quad*4+r
            float4 m4 = *(const float4*)&mb[bs][nt * 16 + quad * 4];
            const float base = fdbase - (float)(nt * 16);
            bf16x4 pv;
            #pragma unroll
            for (int r = 0; r < 4; ++r) {
                float di   = base - (float)r;             // i - j
                float dist = fminf(di, 10.f);
                float e = __expf(cs[r] + dist + ((const float*)&m4)[r]);
                dsum += e;
                pv[r] = (__bf16)e;
            }
            const int irow = 16 * w + m;
            const int jc = nt * 2 + (quad >> 1);          // 8-chunk index
            *(bf16x4*)(&Pb[irow * 64 + ((jc ^ (m & 7)) * 8) + (quad & 1) * 4]) = pv;
        }

        // ---- stage 2: O^T += K^T * P^T (Pb rows wave-private: no barrier) ----
        const int prow = 16 * w + m;
        bf16x8 ap[2];
        #pragma unroll
        for (int k2 = 0; k2 < 2; ++k2)
            ap[k2] = *(const bf16x8*)(&Pb[prow * 64 +
                         (((k2 * 4 + quad) ^ (prow & 7)) * 8)]);
        #pragma unroll
        for (int n2 = 0; n2 < 8; ++n2) {
            const int drow = n2 * 16 + m;                 // KT row = global d
            #pragma unroll
            for (int k2 = 0; k2 < 2; ++k2) {
                bf16x8 av = *(const bf16x8*)(&KTb[bs][drow * 64 +
                               (((k2 * 4 + quad) ^ ktf3(drow)) * 8)]);
                acc[n2] = __builtin_amdgcn_mfma_f32_16x16x32_bf16(av, ap[k2], acc[n2], 0, 0, 0);
            }
        }
    }

    // ---- epilogue: O^T C-layout col = i, rows d = n2*16 + quad*4 + r ----
    dsum += __shfl_xor(dsum, 16);
    dsum += __shfl_xor(dsum, 32);
    const int i = i0 + 16 * w + m;
    const float mi = (mask[b * Tn + i] != 0) ? 1.f : 0.f;
    const float inv = mi / (dsum + EPSF);
    float* orow = out + (size_t)(b * Tn + i) * Dn;
    #pragma unroll
    for (int n2 = 0; n2 < 8; ++n2) {
        float4 o;
        o.x = acc[n2][0] * inv; o.y = acc[n2][1] * inv;
        o.z = acc[n2][2] * inv; o.w = acc[n2][3] * inv;
        *(float4*)(orow + n2 * 16 + quad * 4) = o;
    }
}

// ============================ launch ============================
extern "C" void kernel_launch(void* const* d_in, const int* in_sizes, int n_in,
                              void* d_out, int out_size, void* d_ws, size_t ws_size,
                              hipStream_t stream) {
    const float* x    = (const float*)d_in[0];
    const int*   mask = (const int*)d_in[1];
    float*       out  = (float*)d_out;
    const int B = in_sizes[1] / Tn;          // 32
    const int nblocks = B * (Tn / BM);       // 512, bid%8 == batch%8
    attn_mfma<<<nblocks, 256, 0, stream>>>(x, mask, out);
}